// Round 3
// baseline (428.089 us; speedup 1.0000x reference)
//
#include <hip/hip_runtime.h>
#include <hip/hip_bf16.h>

#define NROWS 65536
#define DIM   1024
#define DF    32
#define NC    5
#define GRID_MAIN 1024   // 1024 blocks x 4 waves = 4096 waves = exactly full residency

typedef __attribute__((ext_vector_type(8))) short bf16x8;
typedef __attribute__((ext_vector_type(4))) float f32x4;

__device__ __forceinline__ unsigned short f2b(float f) {
  // f32 -> bf16 round-to-nearest-even
  unsigned u = __builtin_bit_cast(unsigned, f);
  u += 0x7fffu + ((u >> 16) & 1u);
  return (unsigned short)(u >> 16);
}

// ---------------- kernel 0: pack weights bf16 Wc[48][1024] ------------------
__global__ __launch_bounds__(256) void k_prep(const float* __restrict__ x1_w,
                                              const float* __restrict__ y2_w,
                                              unsigned short* __restrict__ wc) {
  int i = blockIdx.x * 256 + threadIdx.x;  // 0..49151
  int r = i >> 10, k = i & 1023;
  float v = 0.f;
  if (r < DF) v = x1_w[r * DIM + k];
  else if (r < DF + NC) v = y2_w[(r - DF) * DIM + k];
  wc[i] = f2b(v);
}

// ---------------- kernel 1: fused GEMM + heads + gram partials --------------
// wave: 16 rows x 48 cols (3 col-tiles). block: 4 waves = 64 rows; grid 1024.
// C/D layout: col = lane&15, row = (lane>>4)*4 + reg   [m89/m91]
__global__ __launch_bounds__(256, 4) void k_main(const float* __restrict__ x,
                                                 const unsigned short* __restrict__ wc,
                                                 const float* __restrict__ x1_b,
                                                 const float* __restrict__ y1_w,
                                                 const float* __restrict__ y1_b,
                                                 const float* __restrict__ y2_w,
                                                 const float* __restrict__ y2_b,
                                                 float* __restrict__ out,
                                                 float* __restrict__ yp_ws,
                                                 float* __restrict__ ydis_ws,
                                                 float* __restrict__ partials) {
  const int lane = threadIdx.x & 63;
  const int wid  = threadIdx.x >> 6;
  const int c15  = lane & 15;
  const int kg   = lane >> 4;
  const long rowbase = (long)blockIdx.x * 64 + wid * 16;

  const float* ax = x + (rowbase + c15) * DIM + kg * 8;
  const unsigned short* bw0 = wc + (0 * 16 + c15) * DIM + kg * 8;
  const unsigned short* bw1 = wc + (1 * 16 + c15) * DIM + kg * 8;
  const unsigned short* bw2 = wc + (2 * 16 + c15) * DIM + kg * 8;

  f32x4 acc0 = {}, acc1 = {}, acc2 = {};

  // ---- software-pipelined K-loop: loads for step k+1 issue before compute k
  f32x4 alo = *(const f32x4*)(ax);
  f32x4 ahi = *(const f32x4*)(ax + 4);
  bf16x8 b0 = *(const bf16x8*)(bw0);
  bf16x8 b1 = *(const bf16x8*)(bw1);
  bf16x8 b2 = *(const bf16x8*)(bw2);

#define K_BODY()                                                               \
  do {                                                                         \
    bf16x8 a;                                                                  \
    a[0]=(short)f2b(alo[0]); a[1]=(short)f2b(alo[1]);                          \
    a[2]=(short)f2b(alo[2]); a[3]=(short)f2b(alo[3]);                          \
    a[4]=(short)f2b(ahi[0]); a[5]=(short)f2b(ahi[1]);                          \
    a[6]=(short)f2b(ahi[2]); a[7]=(short)f2b(ahi[3]);                          \
    acc0 = __builtin_amdgcn_mfma_f32_16x16x32_bf16(a, b0, acc0, 0, 0, 0);      \
    acc1 = __builtin_amdgcn_mfma_f32_16x16x32_bf16(a, b1, acc1, 0, 0, 0);      \
    acc2 = __builtin_amdgcn_mfma_f32_16x16x32_bf16(a, b2, acc2, 0, 0, 0);      \
  } while (0)

#pragma unroll 2
  for (int kc = 0; kc < DIM - 32; kc += 32) {
    f32x4 nlo = *(const f32x4*)(ax + kc + 32);
    f32x4 nhi = *(const f32x4*)(ax + kc + 36);
    bf16x8 nb0 = *(const bf16x8*)(bw0 + kc + 32);
    bf16x8 nb1 = *(const bf16x8*)(bw1 + kc + 32);
    bf16x8 nb2 = *(const bf16x8*)(bw2 + kc + 32);
    K_BODY();
    alo = nlo; ahi = nhi; b0 = nb0; b1 = nb1; b2 = nb2;
  }
  K_BODY();
#undef K_BODY

  // ---- epilogue: df (f32, in regs) -> yd[2], yp[5] via 16-lane butterflies -
  float w0[7], w1[7];
#pragma unroll
  for (int o = 0; o < 2; ++o) {
    w0[o] = y1_w[o * DF + c15];
    w1[o] = y1_w[o * DF + 16 + c15];
  }
#pragma unroll
  for (int j = 0; j < 5; ++j) {
    w0[2 + j] = y2_w[j * DIM + (DIM - DF) + c15];
    w1[2 + j] = y2_w[j * DIM + (DIM - DF) + 16 + c15];
  }
  const float xb0 = x1_b[c15];
  const float xb1 = x1_b[16 + c15];

  float s[7][4];  // [output][reg] — all indices compile-time (rule #20)
#pragma unroll
  for (int reg = 0; reg < 4; ++reg) {
    float d0 = fmaxf(acc0[reg] + xb0, 0.f);
    float d1 = fmaxf(acc1[reg] + xb1, 0.f);
#pragma unroll
    for (int o = 0; o < 7; ++o) s[o][reg] = fmaf(d0, w0[o], d1 * w1[o]);
  }
  // butterfly reduce across the 16-lane group (masks 1,2,4,8 stay in-group)
#pragma unroll
  for (int m = 1; m <= 8; m <<= 1)
#pragma unroll
    for (int o = 0; o < 7; ++o)
#pragma unroll
      for (int reg = 0; reg < 4; ++reg)
        s[o][reg] += __shfl_xor(s[o][reg], m);

  // y_dataset -> out[N*5 ..] (lanes c15 in {0,1} store), + y1_b bias
  if (c15 < 2) {
    const float yb = y1_b[c15];
#pragma unroll
    for (int reg = 0; reg < 4; ++reg) {
      long row = rowbase + kg * 4 + reg;
      float v = ((c15 == 0) ? s[0][reg] : s[1][reg]) + yb;
      out[(long)NROWS * NC + row * 2 + c15] = v;
    }
  }

  // per-lane yp_k (k = c15) via cndmask chain, ydis_k from acc2
  const float b5 = (c15 < 5) ? y2_b[c15] : 0.f;
  float ypk[4], yv[4];
#pragma unroll
  for (int reg = 0; reg < 4; ++reg) {
    ypk[reg] = (c15 == 0) ? s[2][reg]
             : (c15 == 1) ? s[3][reg]
             : (c15 == 2) ? s[4][reg]
             : (c15 == 3) ? s[5][reg]
                          : s[6][reg];
    yv[reg] = acc2[reg] + b5;
  }
  if (c15 < 5) {
#pragma unroll
    for (int reg = 0; reg < 4; ++reg) {
      long row = rowbase + kg * 4 + reg;
      yp_ws[row * NC + c15]   = ypk[reg];
      ydis_ws[row * NC + c15] = yv[reg];
    }
  }

  // gram / B partials on lanes c15=k<5:  G[j][k]+=yp_j*yp_k, B[j][k]+=yp_j*ydis_k
  float Gp[5] = {0,0,0,0,0}, Bp[5] = {0,0,0,0,0};
#pragma unroll
  for (int reg = 0; reg < 4; ++reg)
#pragma unroll
    for (int j = 0; j < 5; ++j) {
      Gp[j] = fmaf(s[2 + j][reg], ypk[reg], Gp[j]);
      Bp[j] = fmaf(s[2 + j][reg], yv[reg], Bp[j]);
    }
  // reduce across the 4 kg-groups (masks 16, 32 preserve c15)
#pragma unroll
  for (int m = 16; m <= 32; m <<= 1)
#pragma unroll
    for (int j = 0; j < 5; ++j) {
      Gp[j] += __shfl_xor(Gp[j], m);
      Bp[j] += __shfl_xor(Bp[j], m);
    }

  __shared__ float red[4][50];
  if (kg == 0 && c15 < 5) {
#pragma unroll
    for (int j = 0; j < 5; ++j) {
      red[wid][j * 5 + c15]      = Gp[j];
      red[wid][25 + j * 5 + c15] = Bp[j];
    }
  }
  __syncthreads();
  const int tid = threadIdx.x;
  if (tid < 50)
    partials[(long)blockIdx.x * 50 + tid] =
        red[0][tid] + red[1][tid] + red[2][tid] + red[3][tid];  // plain store, no atomics
}

// ---------------- kernel 2: parallel-reduce partials, solve M = G^{-1} B ----
__global__ __launch_bounds__(512) void k_solve(const float* __restrict__ partials,
                                               float* __restrict__ gM) {
  __shared__ float red[8][50];
  __shared__ float g[50];
  const int tid   = threadIdx.x;
  const int c     = tid & 63;   // 0..63, only c<50 active
  const int chunk = tid >> 6;   // 0..7
  if (c < 50) {
    float s = 0.f;
    for (int b = chunk; b < GRID_MAIN; b += 8) s += partials[(long)b * 50 + c];
    red[chunk][c] = s;
  }
  __syncthreads();
  if (tid < 50) {
    float s = 0.f;
#pragma unroll
    for (int k = 0; k < 8; ++k) s += red[k][tid];
    g[tid] = s;
  }
  __syncthreads();
  if (tid == 0) {
    double A[5][10];
    for (int i = 0; i < 5; ++i)
      for (int j = 0; j < 5; ++j) {
        A[i][j]     = (double)g[i * 5 + j];
        A[i][5 + j] = (double)g[25 + i * 5 + j];
      }
    for (int i = 0; i < 5; ++i) {
      int p = i;
      for (int r = i + 1; r < 5; ++r)
        if (fabs(A[r][i]) > fabs(A[p][i])) p = r;
      if (p != i)
        for (int cc = 0; cc < 10; ++cc) { double t = A[i][cc]; A[i][cc] = A[p][cc]; A[p][cc] = t; }
      double inv = 1.0 / A[i][i];
      for (int cc = 0; cc < 10; ++cc) A[i][cc] *= inv;
      for (int r = 0; r < 5; ++r)
        if (r != i) {
          double f = A[r][i];
          for (int cc = 0; cc < 10; ++cc) A[r][cc] -= f * A[i][cc];
        }
    }
    for (int i = 0; i < 5; ++i)
      for (int j = 0; j < 5; ++j) gM[i * 5 + j] = (float)A[i][5 + j];
  }
}

// ---------------- kernel 3: y_hex = y_disease - Yp @ M ----------------------
__global__ __launch_bounds__(256) void k_proj(const float* __restrict__ yp_ws,
                                              const float* __restrict__ ydis_ws,
                                              const float* __restrict__ gM,
                                              float* __restrict__ out) {
  const long row = (long)blockIdx.x * 256 + threadIdx.x;
  float M[25];
#pragma unroll
  for (int i = 0; i < 25; ++i) M[i] = gM[i];
  float yp[NC], yd[NC];
#pragma unroll
  for (int j = 0; j < NC; ++j) {
    yp[j] = yp_ws[row * NC + j];
    yd[j] = ydis_ws[row * NC + j];
  }
#pragma unroll
  for (int c = 0; c < NC; ++c) {
    float p = 0.f;
#pragma unroll
    for (int j = 0; j < NC; ++j) p = fmaf(yp[j], M[j * 5 + c], p);
    out[row * NC + c] = yd[c] - p;
  }
}

// ---------------- launcher --------------------------------------------------
extern "C" void kernel_launch(void* const* d_in, const int* in_sizes, int n_in,
                              void* d_out, int out_size, void* d_ws, size_t ws_size,
                              hipStream_t stream) {
  const float* x    = (const float*)d_in[0];
  const float* x1_w = (const float*)d_in[1];
  const float* x1_b = (const float*)d_in[2];
  const float* y1_w = (const float*)d_in[3];
  const float* y1_b = (const float*)d_in[4];
  const float* y2_w = (const float*)d_in[5];
  const float* y2_b = (const float*)d_in[6];
  float* out = (float*)d_out;
  char* ws = (char*)d_ws;

  // ws layout (bytes, 128B-aligned)
  unsigned short* wc = (unsigned short*)(ws + 0);   //   98304 B: Wc bf16 [48][1024]
  float* partials = (float*)(ws + 98304);           //  204800 B: [1024][50]
  float* gM       = (float*)(ws + 303104);          //     100 B: M [5][5]
  float* yp_ws    = (float*)(ws + 303616);          // 1310720 B: y_padded [N][5]
  float* ydis_ws  = (float*)(ws + 1614336);         // 1310720 B: y_disease [N][5]

  hipLaunchKernelGGL(k_prep,  dim3(192),       dim3(256), 0, stream, x1_w, y2_w, wc);
  hipLaunchKernelGGL(k_main,  dim3(GRID_MAIN), dim3(256), 0, stream, x, wc, x1_b, y1_w, y1_b,
                     y2_w, y2_b, out, yp_ws, ydis_ws, partials);
  hipLaunchKernelGGL(k_solve, dim3(1),         dim3(512), 0, stream, partials, gM);
  hipLaunchKernelGGL(k_proj,  dim3(256),       dim3(256), 0, stream, yp_ws, ydis_ws, gM, out);
}

// Round 4
// 391.354 us; speedup vs baseline: 1.0939x; 1.0939x over previous
//
#include <hip/hip_runtime.h>
#include <hip/hip_bf16.h>

#define NROWS 65536
#define DIM   1024
#define DF    32
#define NC    5

typedef __attribute__((ext_vector_type(8))) short bf16x8;
typedef __attribute__((ext_vector_type(4))) float f32x4;

__device__ __forceinline__ unsigned short f2b(float f) {
  // f32 -> bf16 round-to-nearest-even
  unsigned u = __builtin_bit_cast(unsigned, f);
  u += 0x7fffu + ((u >> 16) & 1u);
  return (unsigned short)(u >> 16);
}

// ---------------- kernel 0: pack weights bf16 Wc[48][1024] + zero G/B accum -
__global__ __launch_bounds__(256) void k_prep(const float* __restrict__ x1_w,
                                              const float* __restrict__ y2_w,
                                              unsigned short* __restrict__ wc,
                                              float* __restrict__ gAcc) {
  if (blockIdx.x == 0 && threadIdx.x < 50) gAcc[threadIdx.x] = 0.f;
  int i = blockIdx.x * 256 + threadIdx.x;  // 0..49151
  int r = i >> 10, k = i & 1023;
  float v = 0.f;
  if (r < DF) v = x1_w[r * DIM + k];
  else if (r < DF + NC) v = y2_w[(r - DF) * DIM + k];
  wc[i] = f2b(v);
}

// ---------------- kernel 1: fused GEMM + small heads + gram partials --------
// wave: 16 rows x 48 cols (3 col-tiles). block: 4 waves = 64 rows; grid 1024.
// C/D layout: col = lane&15, row = (lane>>4)*4 + reg   [m89/m91]
// K-loop kept in the round-2 (measured-best) compiler-scheduled form — the
// round-3 explicit pipeline regressed (+33 us; VGPR pressure under 128-cap).
__global__ __launch_bounds__(256, 4) void k_main(const float* __restrict__ x,
                                                 const unsigned short* __restrict__ wc,
                                                 const float* __restrict__ x1_b,
                                                 const float* __restrict__ y1_w,
                                                 const float* __restrict__ y1_b,
                                                 const float* __restrict__ y2_w,
                                                 const float* __restrict__ y2_b,
                                                 float* __restrict__ out,
                                                 float* __restrict__ yp_ws,
                                                 float* __restrict__ ydis_ws,
                                                 float* __restrict__ gAcc) {
  const int lane = threadIdx.x & 63;
  const int wid  = threadIdx.x >> 6;
  const int c15  = lane & 15;
  const int kg   = lane >> 4;
  const long rowbase = (long)blockIdx.x * 64 + wid * 16;

  const float* ax = x + (rowbase + c15) * DIM + kg * 8;
  const unsigned short* bw0 = wc + (0 * 16 + c15) * DIM + kg * 8;
  const unsigned short* bw1 = wc + (1 * 16 + c15) * DIM + kg * 8;
  const unsigned short* bw2 = wc + (2 * 16 + c15) * DIM + kg * 8;

  f32x4 acc0 = {}, acc1 = {}, acc2 = {};

#pragma unroll 2
  for (int kc = 0; kc < DIM; kc += 32) {
    f32x4 lo = *(const f32x4*)(ax + kc);
    f32x4 hi = *(const f32x4*)(ax + kc + 4);
    bf16x8 a;
    a[0]=(short)f2b(lo[0]); a[1]=(short)f2b(lo[1]); a[2]=(short)f2b(lo[2]); a[3]=(short)f2b(lo[3]);
    a[4]=(short)f2b(hi[0]); a[5]=(short)f2b(hi[1]); a[6]=(short)f2b(hi[2]); a[7]=(short)f2b(hi[3]);
    bf16x8 b0 = *(const bf16x8*)(bw0 + kc);
    bf16x8 b1 = *(const bf16x8*)(bw1 + kc);
    bf16x8 b2 = *(const bf16x8*)(bw2 + kc);
    acc0 = __builtin_amdgcn_mfma_f32_16x16x32_bf16(a, b0, acc0, 0, 0, 0);
    acc1 = __builtin_amdgcn_mfma_f32_16x16x32_bf16(a, b1, acc1, 0, 0, 0);
    acc2 = __builtin_amdgcn_mfma_f32_16x16x32_bf16(a, b2, acc2, 0, 0, 0);
  }

  // ---- epilogue: df (f32, in regs) -> yd[2], yp[5] via 16-lane butterflies -
  float w0[7], w1[7];
#pragma unroll
  for (int o = 0; o < 2; ++o) {
    w0[o] = y1_w[o * DF + c15];
    w1[o] = y1_w[o * DF + 16 + c15];
  }
#pragma unroll
  for (int j = 0; j < 5; ++j) {
    w0[2 + j] = y2_w[j * DIM + (DIM - DF) + c15];
    w1[2 + j] = y2_w[j * DIM + (DIM - DF) + 16 + c15];
  }
  const float xb0 = x1_b[c15];
  const float xb1 = x1_b[16 + c15];

  float s[7][4];  // [output][reg] — all indices compile-time (rule #20)
#pragma unroll
  for (int reg = 0; reg < 4; ++reg) {
    float d0 = fmaxf(acc0[reg] + xb0, 0.f);
    float d1 = fmaxf(acc1[reg] + xb1, 0.f);
#pragma unroll
    for (int o = 0; o < 7; ++o) s[o][reg] = fmaf(d0, w0[o], d1 * w1[o]);
  }
  // butterfly reduce across the 16-lane group (masks 1,2,4,8 stay in-group)
#pragma unroll
  for (int m = 1; m <= 8; m <<= 1)
#pragma unroll
    for (int o = 0; o < 7; ++o)
#pragma unroll
      for (int reg = 0; reg < 4; ++reg)
        s[o][reg] += __shfl_xor(s[o][reg], m);

  // y_dataset -> out[N*5 ..] (lanes c15 in {0,1} store), with y1_b bias
  if (c15 < 2) {
    const float yb = y1_b[c15];
#pragma unroll
    for (int reg = 0; reg < 4; ++reg) {
      long row = rowbase + kg * 4 + reg;
      float v = ((c15 == 0) ? s[0][reg] : s[1][reg]) + yb;
      out[(long)NROWS * NC + row * 2 + c15] = v;
    }
  }

  // per-lane yp_k (k = c15) via cndmask chain, ydis_k from acc2
  const float b5 = (c15 < 5) ? y2_b[c15] : 0.f;
  float ypk[4], yv[4];
#pragma unroll
  for (int reg = 0; reg < 4; ++reg) {
    ypk[reg] = (c15 == 0) ? s[2][reg]
             : (c15 == 1) ? s[3][reg]
             : (c15 == 2) ? s[4][reg]
             : (c15 == 3) ? s[5][reg]
                          : s[6][reg];
    yv[reg] = acc2[reg] + b5;
  }
  // SoA [5][N] stores -> coalesced column streams for k_proj
  if (c15 < 5) {
#pragma unroll
    for (int reg = 0; reg < 4; ++reg) {
      long row = rowbase + kg * 4 + reg;
      yp_ws[(long)c15 * NROWS + row]   = ypk[reg];
      ydis_ws[(long)c15 * NROWS + row] = yv[reg];
    }
  }

  // gram / B partials on lanes c15=k<5:  G[j][k]+=yp_j*yp_k, B[j][k]+=yp_j*ydis_k
  float Gp[5] = {0,0,0,0,0}, Bp[5] = {0,0,0,0,0};
#pragma unroll
  for (int reg = 0; reg < 4; ++reg)
#pragma unroll
    for (int j = 0; j < 5; ++j) {
      Gp[j] = fmaf(s[2 + j][reg], ypk[reg], Gp[j]);
      Bp[j] = fmaf(s[2 + j][reg], yv[reg], Bp[j]);
    }
  // reduce across the 4 kg-groups (masks 16, 32 preserve c15)
#pragma unroll
  for (int m = 16; m <= 32; m <<= 1)
#pragma unroll
    for (int j = 0; j < 5; ++j) {
      Gp[j] += __shfl_xor(Gp[j], m);
      Bp[j] += __shfl_xor(Bp[j], m);
    }

  __shared__ float red[4][50];
  if (kg == 0 && c15 < 5) {
#pragma unroll
    for (int j = 0; j < 5; ++j) {
      red[wid][j * 5 + c15]      = Gp[j];
      red[wid][25 + j * 5 + c15] = Bp[j];
    }
  }
  __syncthreads();
  const int tid = threadIdx.x;
  if (tid < 50)
    atomicAdd(&gAcc[tid], red[0][tid] + red[1][tid] + red[2][tid] + red[3][tid]);
}

// ---------------- kernel 2: per-block solve M = G^{-1}B, then proj ----------
// G is SPD (Yp^T Yp) -> unpivoted Gauss-Jordan in f64 is stable; fully
// unrolled so A[][] stays in registers (runtime pivot index would spill, #20).
__global__ __launch_bounds__(256) void k_proj(const float* __restrict__ yp_ws,
                                              const float* __restrict__ ydis_ws,
                                              const float* __restrict__ gAcc,
                                              float* __restrict__ out) {
  __shared__ float Msh[25];
  if (threadIdx.x == 0) {
    double A[5][10];
#pragma unroll
    for (int i = 0; i < 5; ++i)
#pragma unroll
      for (int j = 0; j < 5; ++j) {
        A[i][j]     = (double)gAcc[i * 5 + j];
        A[i][5 + j] = (double)gAcc[25 + i * 5 + j];
      }
#pragma unroll
    for (int i = 0; i < 5; ++i) {
      double inv = 1.0 / A[i][i];
#pragma unroll
      for (int c = 0; c < 10; ++c) A[i][c] *= inv;
#pragma unroll
      for (int r = 0; r < 5; ++r) {
        if (r == i) continue;
        double f = A[r][i];
#pragma unroll
        for (int c = 0; c < 10; ++c) A[r][c] -= f * A[i][c];
      }
    }
#pragma unroll
    for (int i = 0; i < 5; ++i)
#pragma unroll
      for (int j = 0; j < 5; ++j) Msh[i * 5 + j] = (float)A[i][5 + j];
  }
  __syncthreads();

  const long row = (long)blockIdx.x * 256 + threadIdx.x;
  float yp[NC], yd[NC];
#pragma unroll
  for (int j = 0; j < NC; ++j) {
    yp[j] = yp_ws[(long)j * NROWS + row];
    yd[j] = ydis_ws[(long)j * NROWS + row];
  }
#pragma unroll
  for (int c = 0; c < NC; ++c) {
    float p = 0.f;
#pragma unroll
    for (int j = 0; j < NC; ++j) p = fmaf(yp[j], Msh[j * 5 + c], p);
    out[row * NC + c] = yd[c] - p;
  }
}

// ---------------- launcher --------------------------------------------------
extern "C" void kernel_launch(void* const* d_in, const int* in_sizes, int n_in,
                              void* d_out, int out_size, void* d_ws, size_t ws_size,
                              hipStream_t stream) {
  const float* x    = (const float*)d_in[0];
  const float* x1_w = (const float*)d_in[1];
  const float* x1_b = (const float*)d_in[2];
  const float* y1_w = (const float*)d_in[3];
  const float* y1_b = (const float*)d_in[4];
  const float* y2_w = (const float*)d_in[5];
  const float* y2_b = (const float*)d_in[6];
  float* out = (float*)d_out;
  char* ws = (char*)d_ws;

  // ws layout (bytes, 128B-aligned)
  unsigned short* wc = (unsigned short*)(ws + 0);   //   98304 B: Wc bf16 [48][1024]
  float* gAcc    = (float*)(ws + 98304);            //     200 B: G[25]+B[25] atomic accum
  float* yp_ws   = (float*)(ws + 98816);            // 1310720 B: y_padded SoA [5][N]
  float* ydis_ws = (float*)(ws + 1409536);          // 1310720 B: y_disease SoA [5][N]

  hipLaunchKernelGGL(k_prep, dim3(192),  dim3(256), 0, stream, x1_w, y2_w, wc, gAcc);
  hipLaunchKernelGGL(k_main, dim3(1024), dim3(256), 0, stream, x, wc, x1_b, y1_w, y1_b,
                     y2_w, y2_b, out, yp_ws, ydis_ws, gAcc);
  hipLaunchKernelGGL(k_proj, dim3(256),  dim3(256), 0, stream, yp_ws, ydis_ws, gAcc, out);
}

// Round 5
// 389.465 us; speedup vs baseline: 1.0992x; 1.0048x over previous
//
#include <hip/hip_runtime.h>
#include <hip/hip_bf16.h>

#define NROWS 65536
#define DIM   1024
#define DF    32
#define NC    5

typedef __attribute__((ext_vector_type(8))) short bf16x8;
typedef __attribute__((ext_vector_type(4))) float f32x4;

__device__ __forceinline__ unsigned short f2b(float f) {
  // f32 -> bf16 round-to-nearest-even
  unsigned u = __builtin_bit_cast(unsigned, f);
  u += 0x7fffu + ((u >> 16) & 1u);
  return (unsigned short)(u >> 16);
}

// ---------------- kernel 0: pack weights bf16 Wc[48][1024] + zero G/B accum -
__global__ __launch_bounds__(256) void k_prep(const float* __restrict__ x1_w,
                                              const float* __restrict__ y2_w,
                                              unsigned short* __restrict__ wc,
                                              float* __restrict__ gAcc) {
  if (blockIdx.x == 0 && threadIdx.x < 50) gAcc[threadIdx.x] = 0.f;
  int i = blockIdx.x * 256 + threadIdx.x;  // 0..49151
  int r = i >> 10, k = i & 1023;
  float v = 0.f;
  if (r < DF) v = x1_w[r * DIM + k];
  else if (r < DF + NC) v = y2_w[(r - DF) * DIM + k];
  wc[i] = f2b(v);
}

// ---------------- kernel 1: fused GEMM + small heads + gram partials --------
// wave: 16 rows x 48 cols (3 col-tiles). block: 4 waves = 64 rows; grid 1024.
// C/D layout: col = lane&15, row = (lane>>4)*4 + reg   [m89/m91]
// K-loop: compiler-scheduled (R3 explicit pipeline regressed +33us).
// R5 deltas: unroll 4 (more loads in flight), nontemporal x loads (stream-once,
// keep L2 for wc).
__global__ __launch_bounds__(256, 4) void k_main(const float* __restrict__ x,
                                                 const unsigned short* __restrict__ wc,
                                                 const float* __restrict__ x1_b,
                                                 const float* __restrict__ y1_w,
                                                 const float* __restrict__ y1_b,
                                                 const float* __restrict__ y2_w,
                                                 const float* __restrict__ y2_b,
                                                 float* __restrict__ out,
                                                 float* __restrict__ yp_ws,
                                                 float* __restrict__ ydis_ws,
                                                 float* __restrict__ gAcc) {
  const int lane = threadIdx.x & 63;
  const int wid  = threadIdx.x >> 6;
  const int c15  = lane & 15;
  const int kg   = lane >> 4;
  const long rowbase = (long)blockIdx.x * 64 + wid * 16;

  const float* ax = x + (rowbase + c15) * DIM + kg * 8;
  const unsigned short* bw0 = wc + (0 * 16 + c15) * DIM + kg * 8;
  const unsigned short* bw1 = wc + (1 * 16 + c15) * DIM + kg * 8;
  const unsigned short* bw2 = wc + (2 * 16 + c15) * DIM + kg * 8;

  f32x4 acc0 = {}, acc1 = {}, acc2 = {};

#pragma unroll 4
  for (int kc = 0; kc < DIM; kc += 32) {
    f32x4 lo = __builtin_nontemporal_load((const f32x4*)(ax + kc));
    f32x4 hi = __builtin_nontemporal_load((const f32x4*)(ax + kc + 4));
    bf16x8 a;
    a[0]=(short)f2b(lo[0]); a[1]=(short)f2b(lo[1]); a[2]=(short)f2b(lo[2]); a[3]=(short)f2b(lo[3]);
    a[4]=(short)f2b(hi[0]); a[5]=(short)f2b(hi[1]); a[6]=(short)f2b(hi[2]); a[7]=(short)f2b(hi[3]);
    bf16x8 b0 = *(const bf16x8*)(bw0 + kc);
    bf16x8 b1 = *(const bf16x8*)(bw1 + kc);
    bf16x8 b2 = *(const bf16x8*)(bw2 + kc);
    acc0 = __builtin_amdgcn_mfma_f32_16x16x32_bf16(a, b0, acc0, 0, 0, 0);
    acc1 = __builtin_amdgcn_mfma_f32_16x16x32_bf16(a, b1, acc1, 0, 0, 0);
    acc2 = __builtin_amdgcn_mfma_f32_16x16x32_bf16(a, b2, acc2, 0, 0, 0);
  }

  // ---- epilogue: df (f32, in regs) -> yd[2], yp[5] via 16-lane butterflies -
  float w0[7], w1[7];
#pragma unroll
  for (int o = 0; o < 2; ++o) {
    w0[o] = y1_w[o * DF + c15];
    w1[o] = y1_w[o * DF + 16 + c15];
  }
#pragma unroll
  for (int j = 0; j < 5; ++j) {
    w0[2 + j] = y2_w[j * DIM + (DIM - DF) + c15];
    w1[2 + j] = y2_w[j * DIM + (DIM - DF) + 16 + c15];
  }
  const float xb0 = x1_b[c15];
  const float xb1 = x1_b[16 + c15];

  float s[7][4];  // [output][reg] — all indices compile-time (rule #20)
#pragma unroll
  for (int reg = 0; reg < 4; ++reg) {
    float d0 = fmaxf(acc0[reg] + xb0, 0.f);
    float d1 = fmaxf(acc1[reg] + xb1, 0.f);
#pragma unroll
    for (int o = 0; o < 7; ++o) s[o][reg] = fmaf(d0, w0[o], d1 * w1[o]);
  }
  // butterfly reduce across the 16-lane group (masks 1,2,4,8 stay in-group)
#pragma unroll
  for (int m = 1; m <= 8; m <<= 1)
#pragma unroll
    for (int o = 0; o < 7; ++o)
#pragma unroll
      for (int reg = 0; reg < 4; ++reg)
        s[o][reg] += __shfl_xor(s[o][reg], m);

  // y_dataset -> out[N*5 ..] (lanes c15 in {0,1} store), with y1_b bias
  if (c15 < 2) {
    const float yb = y1_b[c15];
#pragma unroll
    for (int reg = 0; reg < 4; ++reg) {
      long row = rowbase + kg * 4 + reg;
      float v = ((c15 == 0) ? s[0][reg] : s[1][reg]) + yb;
      out[(long)NROWS * NC + row * 2 + c15] = v;
    }
  }

  // per-lane yp_k (k = c15) via cndmask chain, ydis_k from acc2
  const float b5 = (c15 < 5) ? y2_b[c15] : 0.f;
  float ypk[4], yv[4];
#pragma unroll
  for (int reg = 0; reg < 4; ++reg) {
    ypk[reg] = (c15 == 0) ? s[2][reg]
             : (c15 == 1) ? s[3][reg]
             : (c15 == 2) ? s[4][reg]
             : (c15 == 3) ? s[5][reg]
                          : s[6][reg];
    yv[reg] = acc2[reg] + b5;
  }
  // SoA [5][N] stores -> coalesced column streams for k_proj
  if (c15 < 5) {
#pragma unroll
    for (int reg = 0; reg < 4; ++reg) {
      long row = rowbase + kg * 4 + reg;
      yp_ws[(long)c15 * NROWS + row]   = ypk[reg];
      ydis_ws[(long)c15 * NROWS + row] = yv[reg];
    }
  }

  // gram / B partials on lanes c15=k<5:  G[j][k]+=yp_j*yp_k, B[j][k]+=yp_j*ydis_k
  float Gp[5] = {0,0,0,0,0}, Bp[5] = {0,0,0,0,0};
#pragma unroll
  for (int reg = 0; reg < 4; ++reg)
#pragma unroll
    for (int j = 0; j < 5; ++j) {
      Gp[j] = fmaf(s[2 + j][reg], ypk[reg], Gp[j]);
      Bp[j] = fmaf(s[2 + j][reg], yv[reg], Bp[j]);
    }
  // reduce across the 4 kg-groups (masks 16, 32 preserve c15)
#pragma unroll
  for (int m = 16; m <= 32; m <<= 1)
#pragma unroll
    for (int j = 0; j < 5; ++j) {
      Gp[j] += __shfl_xor(Gp[j], m);
      Bp[j] += __shfl_xor(Bp[j], m);
    }

  __shared__ float red[4][50];
  if (kg == 0 && c15 < 5) {
#pragma unroll
    for (int j = 0; j < 5; ++j) {
      red[wid][j * 5 + c15]      = Gp[j];
      red[wid][25 + j * 5 + c15] = Bp[j];
    }
  }
  __syncthreads();
  const int tid = threadIdx.x;
  if (tid < 50)
    atomicAdd(&gAcc[tid], red[0][tid] + red[1][tid] + red[2][tid] + red[3][tid]);
}

// ---------------- kernel 2: per-block solve M = G^{-1}B, then proj ----------
// G is SPD (Yp^T Yp) -> unpivoted Gauss-Jordan in f64 is stable; fully
// unrolled so A[][] stays in registers (runtime pivot index would spill, #20).
__global__ __launch_bounds__(256) void k_proj(const float* __restrict__ yp_ws,
                                              const float* __restrict__ ydis_ws,
                                              const float* __restrict__ gAcc,
                                              float* __restrict__ out) {
  __shared__ float Msh[25];
  if (threadIdx.x == 0) {
    double A[5][10];
#pragma unroll
    for (int i = 0; i < 5; ++i)
#pragma unroll
      for (int j = 0; j < 5; ++j) {
        A[i][j]     = (double)gAcc[i * 5 + j];
        A[i][5 + j] = (double)gAcc[25 + i * 5 + j];
      }
#pragma unroll
    for (int i = 0; i < 5; ++i) {
      double inv = 1.0 / A[i][i];
#pragma unroll
      for (int c = 0; c < 10; ++c) A[i][c] *= inv;
#pragma unroll
      for (int r = 0; r < 5; ++r) {
        if (r == i) continue;
        double f = A[r][i];
#pragma unroll
        for (int c = 0; c < 10; ++c) A[r][c] -= f * A[i][c];
      }
    }
#pragma unroll
    for (int i = 0; i < 5; ++i)
#pragma unroll
      for (int j = 0; j < 5; ++j) Msh[i * 5 + j] = (float)A[i][5 + j];
  }
  __syncthreads();

  const long row = (long)blockIdx.x * 256 + threadIdx.x;
  float yp[NC], yd[NC];
#pragma unroll
  for (int j = 0; j < NC; ++j) {
    yp[j] = yp_ws[(long)j * NROWS + row];
    yd[j] = ydis_ws[(long)j * NROWS + row];
  }
#pragma unroll
  for (int c = 0; c < NC; ++c) {
    float p = 0.f;
#pragma unroll
    for (int j = 0; j < NC; ++j) p = fmaf(yp[j], Msh[j * 5 + c], p);
    out[row * NC + c] = yd[c] - p;
  }
}

// ---------------- launcher --------------------------------------------------
extern "C" void kernel_launch(void* const* d_in, const int* in_sizes, int n_in,
                              void* d_out, int out_size, void* d_ws, size_t ws_size,
                              hipStream_t stream) {
  const float* x    = (const float*)d_in[0];
  const float* x1_w = (const float*)d_in[1];
  const float* x1_b = (const float*)d_in[2];
  const float* y1_w = (const float*)d_in[3];
  const float* y1_b = (const float*)d_in[4];
  const float* y2_w = (const float*)d_in[5];
  const float* y2_b = (const float*)d_in[6];
  float* out = (float*)d_out;
  char* ws = (char*)d_ws;

  // ws layout (bytes, 128B-aligned)
  unsigned short* wc = (unsigned short*)(ws + 0);   //   98304 B: Wc bf16 [48][1024]
  float* gAcc    = (float*)(ws + 98304);            //     200 B: G[25]+B[25] atomic accum
  float* yp_ws   = (float*)(ws + 98816);            // 1310720 B: y_padded SoA [5][N]
  float* ydis_ws = (float*)(ws + 1409536);          // 1310720 B: y_disease SoA [5][N]

  hipLaunchKernelGGL(k_prep, dim3(192),  dim3(256), 0, stream, x1_w, y2_w, wc, gAcc);
  hipLaunchKernelGGL(k_main, dim3(1024), dim3(256), 0, stream, x, wc, x1_b, y1_w, y1_b,
                     y2_w, y2_b, out, yp_ws, ydis_ws, gAcc);
  hipLaunchKernelGGL(k_proj, dim3(256),  dim3(256), 0, stream, yp_ws, ydis_ws, gAcc, out);
}